// Round 13
// baseline (114.726 us; speedup 1.0000x reference)
//
#include <hip/hip_runtime.h>

#define DEG 32
#define HID 32
#define CIN 8

typedef float v2f __attribute__((ext_vector_type(2)));
typedef short bf16x8 __attribute__((ext_vector_type(8)));   // 8 bf16 = 4 VGPRs
typedef float f32x16 __attribute__((ext_vector_type(16)));  // MFMA 32x32 C/D

// gelu(t) = t * rcp(1 + exp2(-t*(A + B*t^2)))   [jax tanh-approx, sigmoid form]
#define GELU_A ((float)(2.0 * 1.4426950408889634 * 0.7978845608028654))
#define GELU_B ((float)(2.0 * 1.4426950408889634 * 0.7978845608028654 * 0.044715))

__device__ __forceinline__ unsigned f2bf(float f) {   // fp32 -> bf16 (RNE)
    unsigned b = __float_as_uint(f);
    return (b + 0x7fffu + ((b >> 16) & 1u)) >> 16;
}
__device__ __forceinline__ unsigned pack2(float lo, float hi) {
    return f2bf(lo) | (f2bf(hi) << 16);
}

// Phase 1: x16[n] = bf16(x[n]) (16 B row -> 1.6 MB gather table, L2-resident);
// w1f / w2f = W1 / W2 in MFMA B-fragment order (frag f: lane l holds
// B[k = f*16 + (l>>5)*8 + j][col = l&31], j=0..7).
__global__ __launch_bounds__(256) void precompute_xw(
    const float* __restrict__ x, const float* __restrict__ W1,
    const float* __restrict__ W2, unsigned* __restrict__ x16,
    unsigned* __restrict__ w1f, unsigned* __restrict__ w2f, int N) {
    int tid = blockIdx.x * 256 + threadIdx.x;
    if (blockIdx.x == 0) {
        int t = threadIdx.x;
        if (t < 64) {                       // W1 fragment (K=16 exactly)
            int kb = (t >> 5) * 8, col = t & 31;
            uint4 o;
            o.x = pack2(W1[(kb + 0) * HID + col], W1[(kb + 1) * HID + col]);
            o.y = pack2(W1[(kb + 2) * HID + col], W1[(kb + 3) * HID + col]);
            o.z = pack2(W1[(kb + 4) * HID + col], W1[(kb + 5) * HID + col]);
            o.w = pack2(W1[(kb + 6) * HID + col], W1[(kb + 7) * HID + col]);
            *(uint4*)(w1f + t * 4) = o;
        } else if (t < 192) {               // W2 fragments (K=32 -> 2 frags)
            int u = t - 64;
            int f = u >> 6, l = u & 63;
            int kb = f * 16 + ((l >> 5) * 8), col = l & 31;
            uint4 o;
            o.x = pack2(W2[(kb + 0) * HID + col], W2[(kb + 1) * HID + col]);
            o.y = pack2(W2[(kb + 2) * HID + col], W2[(kb + 3) * HID + col]);
            o.z = pack2(W2[(kb + 4) * HID + col], W2[(kb + 5) * HID + col]);
            o.w = pack2(W2[(kb + 6) * HID + col], W2[(kb + 7) * HID + col]);
            *(uint4*)(w2f + (f * 64 + l) * 4) = o;
        }
    }
    if (tid < N) {
        const float4* xp = (const float4*)(x + (size_t)tid * CIN);
        float4 a = xp[0], b = xp[1];
        uint4 o;
        o.x = pack2(a.x, a.y);  o.y = pack2(a.z, a.w);
        o.z = pack2(b.x, b.y);  o.w = pack2(b.z, b.w);
        *(uint4*)(x16 + (size_t)tid * 4) = o;
    }
}

// gelu (with bias) + edge-weighted row-sum over one node's C fragment.
// C-layout: col=lane&31 (=hid), row(i) = (i&3) + 8*(i>>2) + 4*(lane>>5).
__device__ __forceinline__ float gelu_reduce(const f32x16& acc, const float* swp,
                                             float b1v) {
    float4 wq0 = *(const float4*)(swp);
    float4 wq1 = *(const float4*)(swp + 8);
    float4 wq2 = *(const float4*)(swp + 16);
    float4 wq3 = *(const float4*)(swp + 24);
    float wqa[16] = {wq0.x, wq0.y, wq0.z, wq0.w,  wq1.x, wq1.y, wq1.z, wq1.w,
                     wq2.x, wq2.y, wq2.z, wq2.w,  wq3.x, wq3.y, wq3.z, wq3.w};
    v2f gacc = {0.f, 0.f};
#pragma unroll
    for (int i = 0; i < 16; i += 2) {
        v2f tt = {acc[i] + b1v, acc[i + 1] + b1v};
        v2f x2 = tt * tt;
        v2f zz = tt * (x2 * (-GELU_B) + (-GELU_A));
        v2f ee;
        ee.x = __builtin_amdgcn_exp2f(zz.x);  ee.y = __builtin_amdgcn_exp2f(zz.y);
        v2f dd = ee + 1.0f;
        v2f rr;
        rr.x = __builtin_amdgcn_rcpf(dd.x);   rr.y = __builtin_amdgcn_rcpf(dd.y);
        v2f wp = {wqa[i], wqa[i + 1]};
        gacc += wp * (tt * rr);                  // gelu = t*sigmoid; exact limits
    }
    float g = gacc.x + gacc.y;
    g += __shfl_xor(g, 32);                      // combine the two row-halves
    return g;
}

// Fused main, BARRIER-FREE: 256-thr block = 4 fully independent waves, each
// owning 2 nodes. Producer: one MFMA [x_j;x_i]@W1 per node + gelu + weighted
// row-sum. Epilogue: per-wave — g rows round-trip a private 128 B LDS patch
// (wave-internal, row index clamped to {0,1}: every lane reads valid data,
// duplicated A rows yield ignored D rows), then 2 MFMAs against W2. The MFMA
// pipe idles at ~4%, so the 4x-redundant per-wave epilogue MFMAs are free.
__global__ __launch_bounds__(256, 6) void git_fused2(
    const unsigned* __restrict__ x16, const unsigned* __restrict__ w1f,
    const unsigned* __restrict__ w2f, const float* __restrict__ wgt,
    const float* __restrict__ b1, const float* __restrict__ b2,
    const int* __restrict__ nbr, float* __restrict__ out, int N) {
    __shared__ float          sw[4][2 * DEG];   // per-wave edge weights
    __shared__ unsigned short sg[4][2 * 32];    // per-wave g rows (2 x 64 B)

    int t = threadIdx.x;
    int wv = t >> 6;                   // wave 0..3 (independent)
    int l  = t & 63;
    int l5 = l & 31;
    int hi = l >> 5;
    int nb = blockIdx.x * 8 + wv * 2;  // this wave's 2 nodes

    int jn[2]; float w[2]; int ncl[2];
#pragma unroll
    for (int r = 0; r < 2; ++r) {
        int n = nb + r; ncl[r] = n < N ? n : (N - 1);
        jn[r] = nbr[ncl[r] * DEG + l5];            // coalesced
        w[r]  = wgt[jn[r]];                        // 400 KB table, cache-hot
    }
    if (hi == 0) {
#pragma unroll
        for (int r = 0; r < 2; ++r) sw[wv][r * DEG + l5] = w[r];
    }

    float ws0, ws1;
    {
        float s = w[0];
        s += __shfl_xor(s, 1);  s += __shfl_xor(s, 2);
        s += __shfl_xor(s, 4);  s += __shfl_xor(s, 8);
        s += __shfl_xor(s, 16);
        ws0 = s;
        s = w[1];
        s += __shfl_xor(s, 1);  s += __shfl_xor(s, 2);
        s += __shfl_xor(s, 4);  s += __shfl_xor(s, 8);
        s += __shfl_xor(s, 16);
        ws1 = s;
    }

    // A-fragment gathers (both in flight): lanes 0-31 x_j, lanes 32-63 x_i
    bf16x8 af0 = *((const bf16x8*)x16 + (hi ? ncl[0] : jn[0]));
    bf16x8 af1 = *((const bf16x8*)x16 + (hi ? ncl[1] : jn[1]));
    bf16x8 bf  = *((const bf16x8*)w1f + l);        // shared W1 fragment
    // hoist epilogue operands (L2-hot) so their latency hides under gelu
    bf16x8 eb1 = *((const bf16x8*)w2f + l);
    bf16x8 eb2 = *((const bf16x8*)w2f + 64 + l);
    float myb1 = b1[l5];
    float myb2 = b2[l5];

    f32x16 z0 = {}, z1 = {};
    f32x16 a0 = __builtin_amdgcn_mfma_f32_32x32x16_bf16(af0, bf, z0, 0, 0, 0);
    f32x16 a1 = __builtin_amdgcn_mfma_f32_32x32x16_bf16(af1, bf, z1, 0, 0, 0);

    const float* swb = &sw[wv][hi * 4];
    float g0 = gelu_reduce(a0, swb, myb1);
    float g1 = gelu_reduce(a1, swb + DEG, myb1);

    // per-wave transpose: lane-indexed g -> bf16 A rows (wave-internal LDS,
    // no barrier; in-order DS ops within a wave)
    if (hi == 0) {
        sg[wv][l5]      = (unsigned short)f2bf(g0);
        sg[wv][32 + l5] = (unsigned short)f2bf(g1);
    }
    int arow = l5 < 2 ? l5 : 1;                    // clamp: rows 2-31 duplicate
    const unsigned short* sgw = &sg[wv][0];
    bf16x8 ea1 = *(const bf16x8*)(sgw + arow * 32 + hi * 8);        // k 0-15
    bf16x8 ea2 = *(const bf16x8*)(sgw + arow * 32 + 16 + hi * 8);   // k 16-31

    f32x16 zz = {};
    f32x16 acc = __builtin_amdgcn_mfma_f32_32x32x16_bf16(ea1, eb1, zz, 0, 0, 0);
    acc = __builtin_amdgcn_mfma_f32_32x32x16_bf16(ea2, eb2, acc, 0, 0, 0);

    // C rows 0,1 (i=0,1 on hi==0 lanes) are this wave's 2 nodes
    if (hi == 0) {
        if (nb < N)
            out[(size_t)nb * HID + l5]       = fmaf(ws0, myb2, acc[0]) * (1.0f / DEG);
        if (nb + 1 < N)
            out[(size_t)(nb + 1) * HID + l5] = fmaf(ws1, myb2, acc[1]) * (1.0f / DEG);
    }
}

// Fallback if d_ws too small: single fused kernel (no workspace tables).
__global__ __launch_bounds__(256) void fused_fallback(
    const float* __restrict__ x, const float* __restrict__ wgt,
    const float* __restrict__ W1, const float* __restrict__ b1,
    const float* __restrict__ W2, const float* __restrict__ b2,
    const int* __restrict__ nbr, float* __restrict__ out, int N) {
    __shared__ float sW2[HID * HID];
    __shared__ float sb2[HID];
    __shared__ int2  sp[8 * DEG];
    int t = threadIdx.x;
#pragma unroll
    for (int i = 0; i < 4; ++i) sW2[t + i * 256] = W2[t + i * 256];
    if (t < HID) sb2[t] = b2[t];
    int slot = t >> 5, hid = t & 31;
    int node = blockIdx.x * 8 + slot;
    bool valid = node < N;
    int nc = valid ? node : (N - 1);
    int   j_own = nbr[nc * DEG + hid];
    float w_own = wgt[j_own];
    sp[slot * DEG + hid] = make_int2(j_own * (CIN * 4), __float_as_int(w_own));
    const float4* xip = (const float4*)(x + (size_t)nc * CIN);
    float4 xa = xip[0], xb = xip[1];
    float w1t[8];
#pragma unroll
    for (int k = 0; k < 8; ++k) w1t[k] = W1[k * HID + hid];
    float vb = b1[hid];
    vb = fmaf(xa.x, W1[ 8 * HID + hid], vb);
    vb = fmaf(xa.y, W1[ 9 * HID + hid], vb);
    vb = fmaf(xa.z, W1[10 * HID + hid], vb);
    vb = fmaf(xa.w, W1[11 * HID + hid], vb);
    vb = fmaf(xb.x, W1[12 * HID + hid], vb);
    vb = fmaf(xb.y, W1[13 * HID + hid], vb);
    vb = fmaf(xb.z, W1[14 * HID + hid], vb);
    vb = fmaf(xb.w, W1[15 * HID + hid], vb);
    float ws = w_own;
    ws += __shfl_xor(ws, 1);  ws += __shfl_xor(ws, 2);
    ws += __shfl_xor(ws, 4);  ws += __shfl_xor(ws, 8);
    ws += __shfl_xor(ws, 16);
    __syncthreads();
    const char* xbytes = (const char*)x;
    const int2* myp = &sp[slot * DEG];
    float g = 0.f;
#pragma unroll 8
    for (int e = 0; e < DEG; ++e) {
        int2  p  = myp[e];
        float wjv = __int_as_float(p.y);
        const float4* xjp = (const float4*)(xbytes + (unsigned)p.x);
        float4 a = xjp[0], b = xjp[1];
        float tin = vb;
        tin = fmaf(a.x, w1t[0], tin); tin = fmaf(a.y, w1t[1], tin);
        tin = fmaf(a.z, w1t[2], tin); tin = fmaf(a.w, w1t[3], tin);
        tin = fmaf(b.x, w1t[4], tin); tin = fmaf(b.y, w1t[5], tin);
        tin = fmaf(b.z, w1t[6], tin); tin = fmaf(b.w, w1t[7], tin);
        float x2 = tin * tin;
        float z  = tin * fmaf(GELU_B, x2, GELU_A);
        float e2 = __builtin_amdgcn_exp2f(z);
        float r  = __builtin_amdgcn_rcpf(1.0f + e2);
        g = fmaf(wjv, fmaf(-tin, r, tin), g);
    }
    float acc = 0.f;
#pragma unroll
    for (int h = 0; h < HID; ++h) {
        float gh = __shfl(g, h, 32);
        acc = fmaf(gh, sW2[h * HID + hid], acc);
    }
    if (valid) out[(size_t)node * HID + hid] = fmaf(ws, sb2[hid], acc) * (1.0f / DEG);
}

extern "C" void kernel_launch(void* const* d_in, const int* in_sizes, int n_in,
                              void* d_out, int out_size, void* d_ws, size_t ws_size,
                              hipStream_t stream) {
    const float* x   = (const float*)d_in[0];
    const float* wq  = (const float*)d_in[1];
    const float* W1  = (const float*)d_in[2];
    const float* b1  = (const float*)d_in[3];
    const float* W2  = (const float*)d_in[4];
    const float* b2  = (const float*)d_in[5];
    const int*   nbr = (const int*)d_in[6];
    float* out = (float*)d_out;

    int N = in_sizes[1];                        // in_weights has N elements

    size_t off_x16 = 0;
    size_t off_w1  = (off_x16 + (size_t)N * 16 + 255) & ~(size_t)255;
    size_t off_w2  = off_w1 + 1024;
    size_t need    = off_w2 + 2048;

    if (ws_size >= need) {
        unsigned* x16 = (unsigned*)((char*)d_ws + off_x16);
        unsigned* w1f = (unsigned*)((char*)d_ws + off_w1);
        unsigned* w2f = (unsigned*)((char*)d_ws + off_w2);

        int blocks_pre = (N + 255) / 256;
        precompute_xw<<<blocks_pre, 256, 0, stream>>>(x, W1, W2, x16, w1f, w2f, N);

        int blocks_main = (N + 7) / 8;          // 8 nodes per 256-thread block
        git_fused2<<<blocks_main, 256, 0, stream>>>(x16, w1f, w2f, wq, b1, b2,
                                                    nbr, out, N);
    } else {
        int blocks = (N + 7) / 8;
        fused_fallback<<<blocks, 256, 0, stream>>>(x, wq, W1, b1, W2, b2, nbr, out, N);
    }
}